// Round 4
// baseline (173.074 us; speedup 1.0000x reference)
//
#include <hip/hip_runtime.h>

// Problem: N=8192 points, D=256 dims, fp32 inputs (L2-normalized rows).
// out[0] = sum_{i,j} [ (s<1-1e-5 ? 1-s : 0) + (s>0.5 ? s : 0) ] / N,  s = q_i . k_j
// out[1] = -mean_i log( sqrt( sum_d (q_i[d] - q_nn(i)[d] + 1e-6)^2 ) ),
//          nn(i) = argmax_{j != i} q_i . q_j   (first index on ties)
//
// Round 4: unfused (fusion regressed: occupancy loss). New schedule:
//  - LDS double-buffer + issue-early staging (T14): STAGE(s+1) before compute(s),
//    ONE barrier per K-step -> the implicit vmcnt(0) drain happens ~620cy after
//    issue, hiding L2 latency (captures T3/T4's benefit without inline asm).
//  - 4-tile bx-sweep per block (16 continuous K-steps) amortizes the prologue
//    drain and overlaps epilogues with the next tile's in-flight loads.

typedef __attribute__((ext_vector_type(8))) short bf16x8;
typedef __attribute__((ext_vector_type(4))) float f32x4;

static constexpr int NPTS = 8192;
static constexpr int DIM  = 256;

__device__ __forceinline__ unsigned short f2bf(float f) {
    unsigned u = __float_as_uint(f);
    u += 0x7FFFu + ((u >> 16) & 1u);   // RNE; inputs are finite
    return (unsigned short)(u >> 16);
}

// async global->LDS, 16B per lane; LDS dest = wave-uniform base + lane*16
__device__ __forceinline__ void gload16(const unsigned short* g, unsigned short* lds) {
    __builtin_amdgcn_global_load_lds(
        (const __attribute__((address_space(1))) unsigned int*)g,
        (__attribute__((address_space(3))) unsigned int*)lds, 16, 0, 0);
}

// ---- fp32 -> bf16 conversion of q and k -------------------------------------
__global__ __launch_bounds__(256) void convert_kernel(
    const float* __restrict__ q, const float* __restrict__ k,
    unsigned short* __restrict__ qbf, unsigned short* __restrict__ kbf)
{
    const int idx = blockIdx.x * 256 + threadIdx.x;
    const int half = NPTS * DIM / 4;
    const float* src = (idx < half) ? q : k;
    unsigned short* dst = (idx < half) ? qbf : kbf;
    const int i = (idx < half) ? idx : idx - half;
    float4 v = reinterpret_cast<const float4*>(src)[i];
    ushort4 o;
    o.x = f2bf(v.x); o.y = f2bf(v.y); o.z = f2bf(v.z); o.w = f2bf(v.w);
    reinterpret_cast<ushort4*>(dst)[i] = o;
}

// ---- GEMM, 128x128 tile, BK=64, 4 waves, bx-sweep of 4 tiles per block ------
// LDS swizzle (proven r2): physical elem = logical elem ^ (8*(row&7)); inverse
// applied to per-lane global source, same XOR on ds_read -> 0 bank conflicts.
// MODE 0: loss accumulated in-reg across sweep -> loss_partial[bid] (1024)
// MODE 1: per-row argmax per tile -> part[bx*N + row] (packed u64), bx=g*4+tile
template<int MODE>
__global__ __launch_bounds__(256, 2) void sim_kernel(
    const unsigned short* __restrict__ A,   // [N][D] bf16 bits
    const unsigned short* __restrict__ B,   // [N][D] bf16 bits
    float* __restrict__ loss_partial,
    unsigned long long* __restrict__ part)
{
    __shared__ __align__(16) unsigned short ldsA[2][128 * 64];
    __shared__ __align__(16) unsigned short ldsB[2][128 * 64];
    __shared__ unsigned long long lds_pack[4][64];
    __shared__ float red[4];

    const int t  = threadIdx.x;
    const int l  = t & 63;
    const int w  = t >> 6;
    const int bid = blockIdx.x;            // 1024 blocks
    const int by  = bid >> 4;              // 0..63 row panel
    const int g   = bid & 15;              // col-tile group (bx = g*4 + tile)
    const int rowbase = by << 7;
    const int wr = (w >> 1) << 6;          // wave row offset: 0 or 64
    const int wc = (w & 1) << 6;           // wave col offset: 0 or 64

    // staging: wave w covers rows [w*32, +32); lane l -> row +l/8, 16B slot l%8;
    // logical elem = 8*((l&7)^(l>>3)) (inverse of read swizzle)
    const int srow = w * 32 + (l >> 3);
    const int scol = 8 * ((l & 7) ^ (l >> 3));
    const unsigned short* gA0 = A + (size_t)(rowbase + srow) * DIM + scol;
    const unsigned short* gB0 = B + (size_t)srow * DIM + scol;

    const int fr = l & 15;     // fragment row within 16
    const int c0 = l >> 4;     // k-slot 0..3
    const int sx = l & 7;      // read-side swizzle xor (== row&7 for frag rows)

    f32x4 acc[4][4];
#pragma unroll
    for (int m = 0; m < 4; m++)
#pragma unroll
        for (int n = 0; n < 4; n++) acc[m][n] = (f32x4){0.f, 0.f, 0.f, 0.f};

    float lsum = 0.f;          // MODE 0 running loss across sweep

    auto STAGE = [&](int s) {  // stage step s into buffer s&1 (async)
        const int kb = s & 3;
        const int tile = s >> 2;
        const unsigned short* a = gA0 + kb * 64;
        const unsigned short* b = gB0 + (size_t)(((g << 2) + tile) << 7) * DIM + kb * 64;
        unsigned short* dA = &ldsA[s & 1][(w * 32) * 64];
        unsigned short* dB = &ldsB[s & 1][(w * 32) * 64];
#pragma unroll
        for (int j = 0; j < 4; j++) {
            gload16(a + (size_t)(j * 8) * DIM, dA + (j * 8) * 64);
            gload16(b + (size_t)(j * 8) * DIM, dB + (j * 8) * 64);
        }
    };

    STAGE(0);
    __syncthreads();           // prologue drain (once per block)

    for (int s = 0; s < 16; s++) {
        if (s < 15) STAGE(s + 1);                 // issue-early: hides under MFMA
        const unsigned short* bufA = &ldsA[s & 1][0];
        const unsigned short* bufB = &ldsB[s & 1][0];
#pragma unroll
        for (int kk = 0; kk < 2; kk++) {
            bf16x8 af[4], bf[4];
#pragma unroll
            for (int m = 0; m < 4; m++) {
                const int row = wr + m * 16 + fr;
                af[m] = *reinterpret_cast<const bf16x8*>(&bufA[row * 64 + 8 * ((kk * 4 + c0) ^ sx)]);
            }
#pragma unroll
            for (int n = 0; n < 4; n++) {
                const int row = wc + n * 16 + fr;
                bf[n] = *reinterpret_cast<const bf16x8*>(&bufB[row * 64 + 8 * ((kk * 4 + c0) ^ sx)]);
            }
#pragma unroll
            for (int m = 0; m < 4; m++)
#pragma unroll
                for (int n = 0; n < 4; n++)
                    acc[m][n] = __builtin_amdgcn_mfma_f32_16x16x32_bf16(af[m], bf[n], acc[m][n], 0, 0, 0);
        }
        __syncthreads();       // reads(s) done for all waves + vmcnt drained (s+1 resident)

        if ((s & 3) == 3) {    // tile finished: epilogue + acc reset (uniform branch)
            const int tile = s >> 2;
            const int colbase = ((g << 2) + tile) << 7;
            if (MODE == 0) {
                const float POS_THR = (float)(1.0 - 1e-5);
#pragma unroll
                for (int m = 0; m < 4; m++)
#pragma unroll
                    for (int n = 0; n < 4; n++)
#pragma unroll
                        for (int v = 0; v < 4; v++) {
                            const float x = acc[m][n][v];
                            lsum += (x < POS_THR ? 1.0f - x : 0.0f) + (x > 0.5f ? x : 0.0f);
                        }
            } else {
                // C/D mapping: col = lane&15 (+n*16), row = (lane>>4)*4 + v (+m*16)
#pragma unroll
                for (int m = 0; m < 4; m++)
#pragma unroll
                    for (int v = 0; v < 4; v++) {
                        const int rlocal = m * 16 + ((l >> 4) << 2) + v;
                        const int grow = rowbase + wr + rlocal;
                        float best = -3.0f;
                        int bcol = 0x7FFFFFFF;
#pragma unroll
                        for (int n = 0; n < 4; n++) {
                            const int gcol = colbase + wc + n * 16 + (l & 15);
                            const float x = acc[m][n][v];
                            const bool valid = (gcol != grow);      // exclude diagonal
                            if (valid && (x > best || (x == best && gcol < bcol))) { best = x; bcol = gcol; }
                        }
#pragma unroll
                        for (int mask = 1; mask < 16; mask <<= 1) { // 16 lanes hold this row
                            const float ob = __shfl_xor(best, mask);
                            const int   oc = __shfl_xor(bcol, mask);
                            if (ob > best || (ob == best && oc < bcol)) { best = ob; bcol = oc; }
                        }
                        if ((l & 15) == 0) {
                            unsigned ub = __float_as_uint(best);
                            unsigned key = (ub & 0x80000000u) ? ~ub : (ub | 0x80000000u);
                            lds_pack[w][rlocal] = ((unsigned long long)key << 32) | (unsigned)(~bcol);
                        }
                    }
                __syncthreads();
                if (t < 128) {
                    const int half = t >> 6;
                    const unsigned long long p0 = lds_pack[half * 2][t & 63];
                    const unsigned long long p1 = lds_pack[half * 2 + 1][t & 63];
                    const unsigned long long p = (p0 > p1) ? p0 : p1;
                    part[(size_t)colbase * 64 + (unsigned)(rowbase + t)] = p;  // colbase*64 = bx*NPTS
                }
            }
#pragma unroll
            for (int m = 0; m < 4; m++)
#pragma unroll
                for (int n = 0; n < 4; n++) acc[m][n] = (f32x4){0.f, 0.f, 0.f, 0.f};
        }
    }

    if (MODE == 0) {
#pragma unroll
        for (int off = 32; off; off >>= 1) lsum += __shfl_down(lsum, off);
        if (l == 0) red[w] = lsum;
        __syncthreads();
        if (t == 0) loss_partial[bid] = red[0] + red[1] + red[2] + red[3];
    }
}

// ---- per-row: combine 64 tile-maxes -> nn idx -> exact fp32 distance -> -log ----
__global__ __launch_bounds__(256) void nn_reg_kernel(
    const float* __restrict__ q, const unsigned long long* __restrict__ part,
    float* __restrict__ reg_partial)
{
    __shared__ float red[4];
    const int t = threadIdx.x, l = t & 63, w = t >> 6;
    const int row = blockIdx.x * 4 + w;
    unsigned long long p = part[(size_t)l * NPTS + (unsigned)row];
#pragma unroll
    for (int mask = 1; mask < 64; mask <<= 1) {
        const unsigned long long o = __shfl_xor(p, mask);
        if (o > p) p = o;
    }
    const int col = (int)(~(unsigned)(p & 0xFFFFFFFFull));
    const float4* q4 = reinterpret_cast<const float4*>(q);
    const float4 a = q4[row * 64 + l];
    const float4 b = q4[col * 64 + l];
    const float dx = a.x - b.x + 1e-6f;
    const float dy = a.y - b.y + 1e-6f;
    const float dz = a.z - b.z + 1e-6f;
    const float dw = a.w - b.w + 1e-6f;
    float s = dx * dx + dy * dy + dz * dz + dw * dw;
#pragma unroll
    for (int mask = 32; mask; mask >>= 1) s += __shfl_xor(s, mask);
    if (l == 0) red[w] = -0.5f * logf(s);   // -log(sqrt(s))
    __syncthreads();
    if (t == 0) reg_partial[blockIdx.x] = red[0] + red[1] + red[2] + red[3];
}

// ---- final double-precision reduction of partials ---------------------------
__global__ __launch_bounds__(256) void finalize_kernel(
    const float* __restrict__ lp, const float* __restrict__ rp, float* __restrict__ out)
{
    const int t = threadIdx.x, l = t & 63, w = t >> 6;
    double s1 = 0.0, s2 = 0.0;
    for (int i = t; i < 1024; i += 256) s1 += (double)lp[i];
    for (int i = t; i < 2048; i += 256) s2 += (double)rp[i];
#pragma unroll
    for (int mask = 32; mask; mask >>= 1) {
        s1 += __shfl_xor(s1, mask);
        s2 += __shfl_xor(s2, mask);
    }
    __shared__ double r1[4], r2[4];
    if (l == 0) { r1[w] = s1; r2[w] = s2; }
    __syncthreads();
    if (t == 0) {
        out[0] = (float)((r1[0] + r1[1] + r1[2] + r1[3]) / (double)NPTS);
        out[1] = (float)((r2[0] + r2[1] + r2[2] + r2[3]) / (double)NPTS);
    }
}

extern "C" void kernel_launch(void* const* d_in, const int* in_sizes, int n_in,
                              void* d_out, int out_size, void* d_ws, size_t ws_size,
                              hipStream_t stream)
{
    const float* q = (const float*)d_in[0];
    const float* k = (const float*)d_in[1];
    char* ws = (char*)d_ws;
    unsigned short* qbf = (unsigned short*)ws;                          // 4 MB
    unsigned short* kbf = (unsigned short*)(ws + (4u << 20));           // 4 MB
    unsigned long long* part = (unsigned long long*)(ws + (8u << 20));  // [64][8192] u64 = 4 MB
    float* lp = (float*)(ws + (12u << 20));                             // 1024 floats
    float* rp = (float*)(ws + (12u << 20) + (16u << 10));               // 2048 floats
    float* out = (float*)d_out;

    convert_kernel<<<4096, 256, 0, stream>>>(q, k, qbf, kbf);
    sim_kernel<0><<<1024, 256, 0, stream>>>(qbf, kbf, lp, nullptr);     // loss over q.k^T
    sim_kernel<1><<<1024, 256, 0, stream>>>(qbf, qbf, nullptr, part);   // argmax over q.q^T
    nn_reg_kernel<<<2048, 256, 0, stream>>>(q, part, rp);
    finalize_kernel<<<1, 256, 0, stream>>>(lp, rp, out);
}

// Round 5
// 160.907 us; speedup vs baseline: 1.0756x; 1.0756x over previous
//
#include <hip/hip_runtime.h>

// Problem: N=8192 points, D=256 dims, fp32 inputs (L2-normalized rows).
// out[0] = sum_{i,j} [ (s<1-1e-5 ? 1-s : 0) + (s>0.5 ? s : 0) ] / N,  s = q_i . k_j
// out[1] = -mean_i log( sqrt( sum_d (q_i[d] - q_nn(i)[d] + 1e-6)^2 ) ),
//          nn(i) = argmax_{j != i} q_i . q_j   (first index on ties)
//
// Round 5: 256x256 block tile, 512 threads (8 waves, 2M x 4N), per-wave 128x64.
// B fragments held in registers across the m-loop -> 43.7 FLOP per LDS byte
// read (vs 32 before); raw s_barrier + counted vmcnt (ONE barrier per K-tile,
// drain covered by ~2400cy of compute). LDS 128KB dbuf -> 1 block/CU.

typedef __attribute__((ext_vector_type(8))) short bf16x8;
typedef __attribute__((ext_vector_type(4))) float f32x4;

static constexpr int NPTS = 8192;
static constexpr int DIM  = 256;

__device__ __forceinline__ unsigned short f2bf(float f) {
    unsigned u = __float_as_uint(f);
    u += 0x7FFFu + ((u >> 16) & 1u);   // RNE; inputs are finite
    return (unsigned short)(u >> 16);
}

// async global->LDS, 16B per lane; LDS dest = wave-uniform base + lane*16
__device__ __forceinline__ void gload16(const unsigned short* g, unsigned short* lds) {
    __builtin_amdgcn_global_load_lds(
        (const __attribute__((address_space(1))) unsigned int*)g,
        (__attribute__((address_space(3))) unsigned int*)lds, 16, 0, 0);
}

// ---- fp32 -> bf16 conversion of q and k -------------------------------------
__global__ __launch_bounds__(256) void convert_kernel(
    const float* __restrict__ q, const float* __restrict__ k,
    unsigned short* __restrict__ qbf, unsigned short* __restrict__ kbf)
{
    const int idx = blockIdx.x * 256 + threadIdx.x;
    const int half = NPTS * DIM / 4;
    const float* src = (idx < half) ? q : k;
    unsigned short* dst = (idx < half) ? qbf : kbf;
    const int i = (idx < half) ? idx : idx - half;
    float4 v = reinterpret_cast<const float4*>(src)[i];
    ushort4 o;
    o.x = f2bf(v.x); o.y = f2bf(v.y); o.z = f2bf(v.z); o.w = f2bf(v.w);
    reinterpret_cast<ushort4*>(dst)[i] = o;
}

// ---- GEMM, 256x256 tile, BK=64, 8 waves, per-wave 128x64 (16x16x32 mfma) ----
// LDS swizzle (proven r2): physical elem = logical elem ^ (8*(row&7)); inverse
// applied to per-lane global source, same XOR on ds_read -> 0 bank conflicts.
// Schedule per K-tile t: [stage tile t+1 -> buf (t+1)&1] [read B frags -> regs]
// [m-loop: read A frag, 8 MFMA] [vmcnt(0) (covered)] [s_barrier].
// MODE 0: loss -> loss_partial[bid].  MODE 1: argmax -> part[bx*N + row].
template<int MODE>
__global__ __launch_bounds__(512, 2) void sim_kernel(
    const unsigned short* __restrict__ A,   // [N][D] bf16 bits
    const unsigned short* __restrict__ B,   // [N][D] bf16 bits
    float* __restrict__ loss_partial,
    unsigned long long* __restrict__ part)
{
    __shared__ __align__(16) unsigned short ldsA[2][256 * 64];  // 64 KB
    __shared__ __align__(16) unsigned short ldsB[2][256 * 64];  // 64 KB
    __shared__ unsigned long long lds_pack[8][128];             // 8 KB (MODE 1)
    __shared__ float red[8];

    const int tid = threadIdx.x;
    const int l   = tid & 63;
    const int w   = tid >> 6;              // 0..7
    const int bid = blockIdx.x;            // 1024 = 32x32 tiles
    const int by  = bid >> 5, bx = bid & 31;
    const int rowbase = by << 8, colbase = bx << 8;
    const int wr = (w >> 2) << 7;          // 0 or 128
    const int wc = (w & 3) << 6;           // 0,64,128,192

    // staging: wave w covers rows [w*32,+32) in 4 issues of 8 rows.
    // lane l -> row +l/8, 16B slot l%8; logical elem = 8*((l&7)^(l>>3))
    const int srow = w * 32 + (l >> 3);
    const int scol = 8 * ((l & 7) ^ (l >> 3));
    const unsigned short* gA0 = A + (size_t)(rowbase + srow) * DIM + scol;
    const unsigned short* gB0 = B + (size_t)(colbase + srow) * DIM + scol;

    const int fr = l & 15;     // fragment row within 16
    const int c0 = l >> 4;     // k-slot 0..3
    const int sx = l & 7;      // read-side swizzle xor (== row&7 for frag rows)

    f32x4 acc[8][4];
#pragma unroll
    for (int m = 0; m < 8; m++)
#pragma unroll
        for (int n = 0; n < 4; n++) acc[m][n] = (f32x4){0.f, 0.f, 0.f, 0.f};

    auto STAGE = [&](int tt) {             // stage K-tile tt into buf tt&1
        unsigned short* dA = &ldsA[tt & 1][(w * 32) * 64];
        unsigned short* dB = &ldsB[tt & 1][(w * 32) * 64];
        const unsigned short* a = gA0 + tt * 64;
        const unsigned short* b = gB0 + tt * 64;
#pragma unroll
        for (int j = 0; j < 4; j++) {
            gload16(a + (size_t)(j * 8) * DIM, dA + (j * 8) * 64);
            gload16(b + (size_t)(j * 8) * DIM, dB + (j * 8) * 64);
        }
    };

    STAGE(0);
    asm volatile("s_waitcnt vmcnt(0)" ::: "memory");
    __builtin_amdgcn_s_barrier();
    asm volatile("" ::: "memory");

    for (int t = 0; t < 4; t++) {
        if (t < 3) STAGE(t + 1);           // issued up-front; covered by compute
        const unsigned short* bufA = &ldsA[t & 1][0];
        const unsigned short* bufB = &ldsB[t & 1][0];
        bf16x8 bh0[4], bh1[4];             // B frags held in regs (kk=0,1)
#pragma unroll
        for (int n = 0; n < 4; n++) {
            const int row = wc + n * 16 + fr;
            bh0[n] = *reinterpret_cast<const bf16x8*>(&bufB[row * 64 + 8 * (c0 ^ sx)]);
            bh1[n] = *reinterpret_cast<const bf16x8*>(&bufB[row * 64 + 8 * ((4 + c0) ^ sx)]);
        }
        __builtin_amdgcn_s_setprio(1);
#pragma unroll
        for (int m = 0; m < 8; m++) {
            const int row = wr + m * 16 + fr;
            const bf16x8 a0 = *reinterpret_cast<const bf16x8*>(&bufA[row * 64 + 8 * (c0 ^ sx)]);
            const bf16x8 a1 = *reinterpret_cast<const bf16x8*>(&bufA[row * 64 + 8 * ((4 + c0) ^ sx)]);
#pragma unroll
            for (int n = 0; n < 4; n++) {
                acc[m][n] = __builtin_amdgcn_mfma_f32_16x16x32_bf16(a0, bh0[n], acc[m][n], 0, 0, 0);
                acc[m][n] = __builtin_amdgcn_mfma_f32_16x16x32_bf16(a1, bh1[n], acc[m][n], 0, 0, 0);
            }
        }
        __builtin_amdgcn_s_setprio(0);
        // tile t reads done (this wave); tile t+1 loads landed (own waves');
        // barrier -> everyone past both -> safe to overwrite buf t&1 next iter
        asm volatile("s_waitcnt vmcnt(0)" ::: "memory");
        __builtin_amdgcn_s_barrier();
        asm volatile("" ::: "memory");
    }

    if (MODE == 0) {
        const float POS_THR = (float)(1.0 - 1e-5);
        float lsum = 0.f;
#pragma unroll
        for (int m = 0; m < 8; m++)
#pragma unroll
            for (int n = 0; n < 4; n++)
#pragma unroll
                for (int v = 0; v < 4; v++) {
                    const float x = acc[m][n][v];
                    lsum += (x < POS_THR ? 1.0f - x : 0.0f) + (x > 0.5f ? x : 0.0f);
                }
#pragma unroll
        for (int off = 32; off; off >>= 1) lsum += __shfl_down(lsum, off);
        if (l == 0) red[w] = lsum;
        __syncthreads();
        if (tid == 0) {
            float s = 0.f;
#pragma unroll
            for (int i = 0; i < 8; i++) s += red[i];
            loss_partial[bid] = s;
        }
    } else {
        // C/D mapping: col = lane&15 (+n*16), row = (lane>>4)*4 + v (+m*16)
#pragma unroll
        for (int m = 0; m < 8; m++)
#pragma unroll
            for (int v = 0; v < 4; v++) {
                const int rlocal = m * 16 + ((l >> 4) << 2) + v;    // 0..127 in wave
                const int grow = rowbase + wr + rlocal;
                float best = -3.0f;
                int bcol = 0x7FFFFFFF;
#pragma unroll
                for (int n = 0; n < 4; n++) {
                    const int gcol = colbase + wc + n * 16 + (l & 15);
                    const float x = acc[m][n][v];
                    const bool valid = (gcol != grow);              // exclude diagonal
                    if (valid && (x > best || (x == best && gcol < bcol))) { best = x; bcol = gcol; }
                }
#pragma unroll
                for (int mask = 1; mask < 16; mask <<= 1) {         // 16 lanes hold this row
                    const float ob = __shfl_xor(best, mask);
                    const int   oc = __shfl_xor(bcol, mask);
                    if (ob > best || (ob == best && oc < bcol)) { best = ob; bcol = oc; }
                }
                if ((l & 15) == 0) {
                    unsigned ub = __float_as_uint(best);
                    unsigned key = (ub & 0x80000000u) ? ~ub : (ub | 0x80000000u);  // order-preserving
                    lds_pack[w][rlocal] = ((unsigned long long)key << 32) | (unsigned)(~bcol);
                }
            }
        __syncthreads();
        if (tid < 256) {
            const int r = tid;                        // block row 0..255
            const int wrg = r >> 7, lr = r & 127;
            unsigned long long p = lds_pack[wrg * 4 + 0][lr];
#pragma unroll
            for (int i = 1; i < 4; i++) {
                const unsigned long long o = lds_pack[wrg * 4 + i][lr];
                if (o > p) p = o;
            }
            part[(size_t)bx * NPTS + (unsigned)(rowbase + r)] = p;   // coalesced 2KB
        }
    }
}

// ---- per-row: combine 32 tile-maxes -> nn idx -> exact fp32 distance -> -log ----
__global__ __launch_bounds__(256) void nn_reg_kernel(
    const float* __restrict__ q, const unsigned long long* __restrict__ part,
    float* __restrict__ reg_partial)
{
    __shared__ float red[4];
    const int t = threadIdx.x, l = t & 63, w = t >> 6;
    const int row = blockIdx.x * 4 + w;
    unsigned long long p = part[(size_t)(l & 31) * NPTS + (unsigned)row];  // lanes 32+ duplicate
#pragma unroll
    for (int mask = 1; mask < 32; mask <<= 1) {
        const unsigned long long o = __shfl_xor(p, mask);
        if (o > p) p = o;
    }
    const int col = (int)(~(unsigned)(p & 0xFFFFFFFFull));
    const float4* q4 = reinterpret_cast<const float4*>(q);
    const float4 a = q4[row * 64 + l];
    const float4 b = q4[col * 64 + l];
    const float dx = a.x - b.x + 1e-6f;
    const float dy = a.y - b.y + 1e-6f;
    const float dz = a.z - b.z + 1e-6f;
    const float dw = a.w - b.w + 1e-6f;
    float s = dx * dx + dy * dy + dz * dz + dw * dw;
#pragma unroll
    for (int mask = 32; mask; mask >>= 1) s += __shfl_xor(s, mask);
    if (l == 0) red[w] = -0.5f * logf(s);   // -log(sqrt(s))
    __syncthreads();
    if (t == 0) reg_partial[blockIdx.x] = red[0] + red[1] + red[2] + red[3];
}

// ---- final double-precision reduction of partials ---------------------------
__global__ __launch_bounds__(256) void finalize_kernel(
    const float* __restrict__ lp, const float* __restrict__ rp, float* __restrict__ out)
{
    const int t = threadIdx.x, l = t & 63, w = t >> 6;
    double s1 = 0.0, s2 = 0.0;
    for (int i = t; i < 1024; i += 256) s1 += (double)lp[i];
    for (int i = t; i < 2048; i += 256) s2 += (double)rp[i];
#pragma unroll
    for (int mask = 32; mask; mask >>= 1) {
        s1 += __shfl_xor(s1, mask);
        s2 += __shfl_xor(s2, mask);
    }
    __shared__ double r1[4], r2[4];
    if (l == 0) { r1[w] = s1; r2[w] = s2; }
    __syncthreads();
    if (t == 0) {
        out[0] = (float)((r1[0] + r1[1] + r1[2] + r1[3]) / (double)NPTS);
        out[1] = (float)((r2[0] + r2[1] + r2[2] + r2[3]) / (double)NPTS);
    }
}

extern "C" void kernel_launch(void* const* d_in, const int* in_sizes, int n_in,
                              void* d_out, int out_size, void* d_ws, size_t ws_size,
                              hipStream_t stream)
{
    const float* q = (const float*)d_in[0];
    const float* k = (const float*)d_in[1];
    char* ws = (char*)d_ws;
    unsigned short* qbf = (unsigned short*)ws;                          // 4 MB
    unsigned short* kbf = (unsigned short*)(ws + (4u << 20));           // 4 MB
    unsigned long long* part = (unsigned long long*)(ws + (8u << 20));  // [32][8192] u64 = 2 MB
    float* lp = (float*)(ws + (11u << 20));                             // 1024 floats
    float* rp = (float*)(ws + (11u << 20) + (16u << 10));               // 2048 floats
    float* out = (float*)d_out;

    convert_kernel<<<4096, 256, 0, stream>>>(q, k, qbf, kbf);
    sim_kernel<0><<<1024, 512, 0, stream>>>(qbf, kbf, lp, nullptr);     // loss over q.k^T
    sim_kernel<1><<<1024, 512, 0, stream>>>(qbf, qbf, nullptr, part);   // argmax over q.q^T
    nn_reg_kernel<<<2048, 256, 0, stream>>>(q, part, rp);
    finalize_kernel<<<1, 256, 0, stream>>>(lp, rp, out);
}

// Round 6
// 144.840 us; speedup vs baseline: 1.1949x; 1.1109x over previous
//
#include <hip/hip_runtime.h>

// Problem: N=8192 points, D=256 dims, fp32 inputs (L2-normalized rows).
// out[0] = sum_{i,j} [ (s<1-1e-5 ? 1-s : 0) + (s>0.5 ? s : 0) ] / N,  s = q_i . k_j
// out[1] = -mean_i log( sqrt( sum_d (q_i[d] - q_nn(i)[d] + 1e-6)^2 ) ),
//          nn(i) = argmax_{j != i} q_i . q_j   (first index on ties)
//
// Round 6: revert to the round-2 champion structure (128^2 tile, 4 waves,
// single-buffer LDS, ~3 blocks/CU — occupancy beats schedule tricks at K=256).
// Algorithmic win: q.q^T is SYMMETRIC -> compute only upper-triangle tiles
// (by <= bx, 2080 of 4096 blocks); each off-diagonal tile yields the row-max
// (rows of panel by over j-panel bx) AND the col-max (= row-max for rows of
// panel bx over j-panel by, by symmetry).

typedef __attribute__((ext_vector_type(8))) short bf16x8;
typedef __attribute__((ext_vector_type(4))) float f32x4;

static constexpr int NPTS = 8192;
static constexpr int DIM  = 256;

__device__ __forceinline__ unsigned short f2bf(float f) {
    unsigned u = __float_as_uint(f);
    u += 0x7FFFu + ((u >> 16) & 1u);   // RNE; inputs are finite
    return (unsigned short)(u >> 16);
}

// async global->LDS, 16B per lane; LDS dest = wave-uniform base + lane*16
__device__ __forceinline__ void gload16(const unsigned short* g, unsigned short* lds) {
    __builtin_amdgcn_global_load_lds(
        (const __attribute__((address_space(1))) unsigned int*)g,
        (__attribute__((address_space(3))) unsigned int*)lds, 16, 0, 0);
}

__device__ __forceinline__ unsigned long long packkey(float v, int idx) {
    unsigned ub = __float_as_uint(v);
    unsigned key = (ub & 0x80000000u) ? ~ub : (ub | 0x80000000u);  // order-preserving
    return ((unsigned long long)key << 32) | (unsigned)(~idx);     // larger val, then smaller idx
}

// ---- fp32 -> bf16 conversion of q and k -------------------------------------
__global__ __launch_bounds__(256) void convert_kernel(
    const float* __restrict__ q, const float* __restrict__ k,
    unsigned short* __restrict__ qbf, unsigned short* __restrict__ kbf)
{
    const int idx = blockIdx.x * 256 + threadIdx.x;
    const int half = NPTS * DIM / 4;
    const float* src = (idx < half) ? q : k;
    unsigned short* dst = (idx < half) ? qbf : kbf;
    const int i = (idx < half) ? idx : idx - half;
    float4 v = reinterpret_cast<const float4*>(src)[i];
    ushort4 o;
    o.x = f2bf(v.x); o.y = f2bf(v.y); o.z = f2bf(v.z); o.w = f2bf(v.w);
    reinterpret_cast<ushort4*>(dst)[i] = o;
}

// ---- loss GEMM: 128x128 tile, BK=64, 4 waves (byte-identical to round 2) ----
__global__ __launch_bounds__(256) void sim_loss_kernel(
    const unsigned short* __restrict__ A,   // q bf16
    const unsigned short* __restrict__ B,   // k bf16
    float* __restrict__ loss_partial)
{
    __shared__ __align__(16) unsigned short ldsA[128 * 64];
    __shared__ __align__(16) unsigned short ldsB[128 * 64];
    __shared__ float red[4];

    const int t  = threadIdx.x;
    const int l  = t & 63;
    const int w  = t >> 6;
    const int bid = blockIdx.x;
    const int bx = bid & 63;
    const int by = bid >> 6;
    const int rowbase = by << 7;
    const int colbase = bx << 7;
    const int wr = (w >> 1) << 6;
    const int wc = (w & 1) << 6;

    const int srow = w * 32 + (l >> 3);
    const int scol = 8 * ((l & 7) ^ (l >> 3));
    const unsigned short* gA = A + (size_t)(rowbase + srow) * DIM + scol;
    const unsigned short* gB = B + (size_t)(colbase + srow) * DIM + scol;

    f32x4 acc[4][4];
#pragma unroll
    for (int m = 0; m < 4; m++)
#pragma unroll
        for (int n = 0; n < 4; n++) acc[m][n] = (f32x4){0.f, 0.f, 0.f, 0.f};

    const int fr = l & 15;
    const int c0 = l >> 4;
    const int sx = l & 7;

    for (int kb = 0; kb < DIM / 64; kb++) {
#pragma unroll
        for (int j = 0; j < 4; j++) {
            gload16(gA + (size_t)(j * 8) * DIM, &ldsA[(w * 32 + j * 8) * 64]);
            gload16(gB + (size_t)(j * 8) * DIM, &ldsB[(w * 32 + j * 8) * 64]);
        }
        gA += 64; gB += 64;
        __syncthreads();
#pragma unroll
        for (int kk = 0; kk < 2; kk++) {
            bf16x8 af[4], bfr[4];
#pragma unroll
            for (int m = 0; m < 4; m++) {
                const int row = wr + m * 16 + fr;
                af[m] = *reinterpret_cast<const bf16x8*>(&ldsA[row * 64 + 8 * ((kk * 4 + c0) ^ sx)]);
            }
#pragma unroll
            for (int n = 0; n < 4; n++) {
                const int row = wc + n * 16 + fr;
                bfr[n] = *reinterpret_cast<const bf16x8*>(&ldsB[row * 64 + 8 * ((kk * 4 + c0) ^ sx)]);
            }
#pragma unroll
            for (int m = 0; m < 4; m++)
#pragma unroll
                for (int n = 0; n < 4; n++)
                    acc[m][n] = __builtin_amdgcn_mfma_f32_16x16x32_bf16(af[m], bfr[n], acc[m][n], 0, 0, 0);
        }
        __syncthreads();
    }

    const float POS_THR = (float)(1.0 - 1e-5);
    float s = 0.f;
#pragma unroll
    for (int m = 0; m < 4; m++)
#pragma unroll
        for (int n = 0; n < 4; n++)
#pragma unroll
            for (int v = 0; v < 4; v++) {
                const float x = acc[m][n][v];
                s += (x < POS_THR ? 1.0f - x : 0.0f) + (x > 0.5f ? x : 0.0f);
            }
#pragma unroll
    for (int off = 32; off; off >>= 1) s += __shfl_down(s, off);
    if (l == 0) red[w] = s;
    __syncthreads();
    if (t == 0) loss_partial[bid] = red[0] + red[1] + red[2] + red[3];
}

// ---- argmax GEMM over UPPER TRIANGLE of q.q^T: 2080 tiles (by <= bx) --------
// Row-max -> part[bx][rowbase+r]; col-max (by<bx only) -> part[by][colbase+c].
__global__ __launch_bounds__(256) void sim_tri_kernel(
    const unsigned short* __restrict__ Qb,
    unsigned long long* __restrict__ part)
{
    __shared__ __align__(16) unsigned short ldsA[128 * 64];
    __shared__ __align__(16) unsigned short ldsB[128 * 64];
    __shared__ unsigned long long lds_pack[4][64];   // row-max per wave
    __shared__ unsigned long long colpack[4][64];    // col-max per wave

    const int t  = threadIdx.x;
    const int l  = t & 63;
    const int w  = t >> 6;

    // triangle decode: row by has 64-by tiles (bx = by..63)
    int r0 = blockIdx.x, by = 0;
    while (r0 >= 64 - by) { r0 -= 64 - by; ++by; }
    const int bx = by + r0;

    const int rowbase = by << 7;
    const int colbase = bx << 7;
    const int wr = (w >> 1) << 6;
    const int wc = (w & 1) << 6;

    const int srow = w * 32 + (l >> 3);
    const int scol = 8 * ((l & 7) ^ (l >> 3));
    const unsigned short* gA = Qb + (size_t)(rowbase + srow) * DIM + scol;
    const unsigned short* gB = Qb + (size_t)(colbase + srow) * DIM + scol;

    f32x4 acc[4][4];
#pragma unroll
    for (int m = 0; m < 4; m++)
#pragma unroll
        for (int n = 0; n < 4; n++) acc[m][n] = (f32x4){0.f, 0.f, 0.f, 0.f};

    const int fr = l & 15;
    const int c0 = l >> 4;
    const int sx = l & 7;

    for (int kb = 0; kb < DIM / 64; kb++) {
#pragma unroll
        for (int j = 0; j < 4; j++) {
            gload16(gA + (size_t)(j * 8) * DIM, &ldsA[(w * 32 + j * 8) * 64]);
            gload16(gB + (size_t)(j * 8) * DIM, &ldsB[(w * 32 + j * 8) * 64]);
        }
        gA += 64; gB += 64;
        __syncthreads();
#pragma unroll
        for (int kk = 0; kk < 2; kk++) {
            bf16x8 af[4], bfr[4];
#pragma unroll
            for (int m = 0; m < 4; m++) {
                const int row = wr + m * 16 + fr;
                af[m] = *reinterpret_cast<const bf16x8*>(&ldsA[row * 64 + 8 * ((kk * 4 + c0) ^ sx)]);
            }
#pragma unroll
            for (int n = 0; n < 4; n++) {
                const int row = wc + n * 16 + fr;
                bfr[n] = *reinterpret_cast<const bf16x8*>(&ldsB[row * 64 + 8 * ((kk * 4 + c0) ^ sx)]);
            }
#pragma unroll
            for (int m = 0; m < 4; m++)
#pragma unroll
                for (int n = 0; n < 4; n++)
                    acc[m][n] = __builtin_amdgcn_mfma_f32_16x16x32_bf16(af[m], bfr[n], acc[m][n], 0, 0, 0);
        }
        __syncthreads();
    }

    // ---- row-max (rows of panel by, cols of panel bx, diag excluded) ----
    // C/D mapping: col = lane&15 (+n*16), row = (lane>>4)*4 + v (+m*16)
#pragma unroll
    for (int m = 0; m < 4; m++)
#pragma unroll
        for (int v = 0; v < 4; v++) {
            const int rlocal = m * 16 + ((l >> 4) << 2) + v;    // 0..63 within wave
            const int grow = rowbase + wr + rlocal;
            float best = -3.0f;
            int bcol = 0x7FFFFFFF;
#pragma unroll
            for (int n = 0; n < 4; n++) {
                const int gcol = colbase + wc + n * 16 + (l & 15);
                const float x = acc[m][n][v];
                const bool valid = (gcol != grow);              // exclude diagonal
                if (valid && (x > best || (x == best && gcol < bcol))) { best = x; bcol = gcol; }
            }
#pragma unroll
            for (int mask = 1; mask < 16; mask <<= 1) {         // 16 lanes hold this row
                const float ob = __shfl_xor(best, mask);
                const int   oc = __shfl_xor(bcol, mask);
                if (ob > best || (ob == best && oc < bcol)) { best = ob; bcol = oc; }
            }
            if ((l & 15) == 0) lds_pack[w][rlocal] = packkey(best, bcol);
        }

    // ---- col-max (by<bx): for cols of panel bx, argmax over rows of panel by ----
    if (by < bx) {
#pragma unroll
        for (int n = 0; n < 4; n++) {
            float cbest = -3.0f;
            int crow = 0x7FFFFFFF;
#pragma unroll
            for (int m = 0; m < 4; m++)
#pragma unroll
                for (int v = 0; v < 4; v++) {
                    const int grow = rowbase + wr + m * 16 + ((l >> 4) << 2) + v;
                    const float x = acc[m][n][v];
                    if (x > cbest || (x == cbest && grow < crow)) { cbest = x; crow = grow; }
                }
            // combine the 4 row-groups (lanes sharing l&15)
#pragma unroll
            for (int mask = 16; mask < 64; mask <<= 1) {
                const float ob = __shfl_xor(cbest, mask);
                const int   oc = __shfl_xor(crow, mask);
                if (ob > cbest || (ob == cbest && oc < crow)) { cbest = ob; crow = oc; }
            }
            if ((l >> 4) == 0) colpack[w][n * 16 + l] = packkey(cbest, crow);
        }
    }
    __syncthreads();

    if (t < 128) {
        // row-max write: rows rowbase+t, j-panel bx
        const int half = t >> 6;                      // waves {0,1}: rows 0-63; {2,3}: 64-127
        const unsigned long long p0 = lds_pack[half * 2][t & 63];
        const unsigned long long p1 = lds_pack[half * 2 + 1][t & 63];
        part[(size_t)bx * NPTS + (unsigned)(rowbase + t)] = (p0 > p1) ? p0 : p1;
        if (by < bx) {
            // col-max write: "rows" colbase+t, j-panel by. waves {0,2}: wc=0; {1,3}: wc=64
            const int h = t >> 6;                     // col half
            const unsigned long long c0_ = colpack[h][t & 63];
            const unsigned long long c1_ = colpack[h + 2][t & 63];
            part[(size_t)by * NPTS + (unsigned)(colbase + t)] = (c0_ > c1_) ? c0_ : c1_;
        }
    }
}

// ---- per-row: combine 64 tile-maxes -> nn idx -> exact fp32 distance -> -log ----
__global__ __launch_bounds__(256) void nn_reg_kernel(
    const float* __restrict__ q, const unsigned long long* __restrict__ part,
    float* __restrict__ reg_partial)
{
    __shared__ float red[4];
    const int t = threadIdx.x, l = t & 63, w = t >> 6;
    const int row = blockIdx.x * 4 + w;
    unsigned long long p = part[(size_t)l * NPTS + (unsigned)row];
#pragma unroll
    for (int mask = 1; mask < 64; mask <<= 1) {
        const unsigned long long o = __shfl_xor(p, mask);
        if (o > p) p = o;
    }
    const int col = (int)(~(unsigned)(p & 0xFFFFFFFFull));
    const float4* q4 = reinterpret_cast<const float4*>(q);
    const float4 a = q4[row * 64 + l];
    const float4 b = q4[col * 64 + l];
    const float dx = a.x - b.x + 1e-6f;
    const float dy = a.y - b.y + 1e-6f;
    const float dz = a.z - b.z + 1e-6f;
    const float dw = a.w - b.w + 1e-6f;
    float s = dx * dx + dy * dy + dz * dz + dw * dw;
#pragma unroll
    for (int mask = 32; mask; mask >>= 1) s += __shfl_xor(s, mask);
    if (l == 0) red[w] = -0.5f * logf(s);   // -log(sqrt(s))
    __syncthreads();
    if (t == 0) reg_partial[blockIdx.x] = red[0] + red[1] + red[2] + red[3];
}

// ---- final double-precision reduction of partials ---------------------------
__global__ __launch_bounds__(256) void finalize_kernel(
    const float* __restrict__ lp, const float* __restrict__ rp, float* __restrict__ out)
{
    const int t = threadIdx.x, l = t & 63, w = t >> 6;
    double s1 = 0.0, s2 = 0.0;
    for (int i = t; i < 4096; i += 256) s1 += (double)lp[i];
    for (int i = t; i < 2048; i += 256) s2 += (double)rp[i];
#pragma unroll
    for (int mask = 32; mask; mask >>= 1) {
        s1 += __shfl_xor(s1, mask);
        s2 += __shfl_xor(s2, mask);
    }
    __shared__ double r1[4], r2[4];
    if (l == 0) { r1[w] = s1; r2[w] = s2; }
    __syncthreads();
    if (t == 0) {
        out[0] = (float)((r1[0] + r1[1] + r1[2] + r1[3]) / (double)NPTS);
        out[1] = (float)((r2[0] + r2[1] + r2[2] + r2[3]) / (double)NPTS);
    }
}

extern "C" void kernel_launch(void* const* d_in, const int* in_sizes, int n_in,
                              void* d_out, int out_size, void* d_ws, size_t ws_size,
                              hipStream_t stream)
{
    const float* q = (const float*)d_in[0];
    const float* k = (const float*)d_in[1];
    char* ws = (char*)d_ws;
    unsigned short* qbf = (unsigned short*)ws;                          // 4 MB
    unsigned short* kbf = (unsigned short*)(ws + (4u << 20));           // 4 MB
    unsigned long long* part = (unsigned long long*)(ws + (8u << 20));  // [64][8192] u64 = 4 MB
    float* lp = (float*)(ws + (12u << 20));                             // 4096 floats
    float* rp = (float*)(ws + (12u << 20) + (16u << 10));               // 2048 floats
    float* out = (float*)d_out;

    convert_kernel<<<4096, 256, 0, stream>>>(q, k, qbf, kbf);
    sim_loss_kernel<<<4096, 256, 0, stream>>>(qbf, kbf, lp);            // loss over q.k^T
    sim_tri_kernel<<<2080, 256, 0, stream>>>(qbf, part);                // argmax over q.q^T (triangle)
    nn_reg_kernel<<<2048, 256, 0, stream>>>(q, part, rp);
    finalize_kernel<<<1, 256, 0, stream>>>(lp, rp, out);
}

// Round 7
// 118.835 us; speedup vs baseline: 1.4564x; 1.2188x over previous
//
#include <hip/hip_runtime.h>

// Problem: N=8192 points, D=256 dims, fp32 inputs (L2-normalized rows).
// out[0] = sum_{i,j} [ (s<1-1e-5 ? 1-s : 0) + (s>0.5 ? s : 0) ] / N,  s = q_i . k_j
// out[1] = -mean_i log( sqrt( sum_d (q_i[d] - q_nn(i)[d] + 1e-6)^2 ) ),
//          nn(i) = argmax_{j != i} q_i . q_j   (first index on ties)
//
// Round 7: ONE merged GEMM dispatch: 6176 blocks = 4096 loss (q.k^T) + 2080
// triangle argmax (q.q^T, by<=bx, row+col max by symmetry), Bresenham-
// interleaved 2:1 so every CU co-hosts both block types (stall-filling per
// m114; the regime is barrier/stall-bound: MfmaUtil+VALUBusy < 40%).
// K-loop is shared code; only epilogues branch (block-uniform).

typedef __attribute__((ext_vector_type(8))) short bf16x8;
typedef __attribute__((ext_vector_type(4))) float f32x4;

static constexpr int NPTS = 8192;
static constexpr int DIM  = 256;
static constexpr int NTRI = 2080;            // 64*65/2 triangle tiles
static constexpr int NLOSS = 4096;           // 64*64 loss tiles
static constexpr int NGRID = NTRI + NLOSS;   // 6176

__device__ __forceinline__ unsigned short f2bf(float f) {
    unsigned u = __float_as_uint(f);
    u += 0x7FFFu + ((u >> 16) & 1u);   // RNE; inputs are finite
    return (unsigned short)(u >> 16);
}

// async global->LDS, 16B per lane; LDS dest = wave-uniform base + lane*16
__device__ __forceinline__ void gload16(const unsigned short* g, unsigned short* lds) {
    __builtin_amdgcn_global_load_lds(
        (const __attribute__((address_space(1))) unsigned int*)g,
        (__attribute__((address_space(3))) unsigned int*)lds, 16, 0, 0);
}

__device__ __forceinline__ unsigned long long packkey(float v, int idx) {
    unsigned ub = __float_as_uint(v);
    unsigned key = (ub & 0x80000000u) ? ~ub : (ub | 0x80000000u);  // order-preserving
    return ((unsigned long long)key << 32) | (unsigned)(~idx);     // larger val, then smaller idx
}

// ---- fp32 -> bf16 conversion of q and k -------------------------------------
__global__ __launch_bounds__(256) void convert_kernel(
    const float* __restrict__ q, const float* __restrict__ k,
    unsigned short* __restrict__ qbf, unsigned short* __restrict__ kbf)
{
    const int idx = blockIdx.x * 256 + threadIdx.x;
    const int half = NPTS * DIM / 4;
    const float* src = (idx < half) ? q : k;
    unsigned short* dst = (idx < half) ? qbf : kbf;
    const int i = (idx < half) ? idx : idx - half;
    float4 v = reinterpret_cast<const float4*>(src)[i];
    ushort4 o;
    o.x = f2bf(v.x); o.y = f2bf(v.y); o.z = f2bf(v.z); o.w = f2bf(v.w);
    reinterpret_cast<ushort4*>(dst)[i] = o;
}

// ---- merged GEMM: 128x128 tile, BK=64, 4 waves, shared K-loop ---------------
// LDS swizzle (proven r2): physical elem = logical elem ^ (8*(row&7)); inverse
// applied to per-lane global source, same XOR on ds_read -> 0 bank conflicts.
__global__ __launch_bounds__(256, 4) void sim_merged_kernel(
    const unsigned short* __restrict__ Qb,  // [N][D] bf16 bits
    const unsigned short* __restrict__ Kb,  // [N][D] bf16 bits
    float* __restrict__ loss_partial,       // [4096]
    unsigned long long* __restrict__ part)  // [64][8192]
{
    __shared__ __align__(16) unsigned short ldsA[128 * 64];
    __shared__ __align__(16) unsigned short ldsB[128 * 64];
    __shared__ unsigned long long lds_pack[4][64];   // row-max per wave (tri)
    __shared__ unsigned long long colpack[4][64];    // col-max per wave (tri)
    __shared__ float red[4];                         // loss reduce

    const int t  = threadIdx.x;
    const int l  = t & 63;
    const int w  = t >> 6;
    const int bid = blockIdx.x;

    // Bresenham 2:1 interleave of 4096 loss + 2080 tri blocks
    const int tb = (int)(((long long)bid * NTRI) / NGRID);
    const int ta = (int)(((long long)(bid + 1) * NTRI) / NGRID);
    const bool is_tri = (ta > tb);

    int by, bx;
    const unsigned short* Bsrc;
    if (is_tri) {
        int r0 = tb;                       // tri index 0..2079: row by has 64-by tiles
        by = 0;
        while (r0 >= 64 - by) { r0 -= 64 - by; ++by; }
        bx = by + r0;
        Bsrc = Qb;
    } else {
        const int li = bid - tb;           // loss index 0..4095
        by = li >> 6; bx = li & 63;
        Bsrc = Kb;
    }

    const int rowbase = by << 7;
    const int colbase = bx << 7;
    const int wr = (w >> 1) << 6;
    const int wc = (w & 1) << 6;

    // staging: wave w covers rows [w*32,+32); lane l -> row +l/8, slot l%8;
    // logical elem = 8*((l&7)^(l>>3)) (inverse of read swizzle)
    const int srow = w * 32 + (l >> 3);
    const int scol = 8 * ((l & 7) ^ (l >> 3));
    const unsigned short* gA = Qb   + (size_t)(rowbase + srow) * DIM + scol;
    const unsigned short* gB = Bsrc + (size_t)(colbase + srow) * DIM + scol;

    f32x4 acc[4][4];
#pragma unroll
    for (int m = 0; m < 4; m++)
#pragma unroll
        for (int n = 0; n < 4; n++) acc[m][n] = (f32x4){0.f, 0.f, 0.f, 0.f};

    const int fr = l & 15;
    const int c0 = l >> 4;
    const int sx = l & 7;

    for (int kb = 0; kb < DIM / 64; kb++) {
#pragma unroll
        for (int j = 0; j < 4; j++) {
            gload16(gA + (size_t)(j * 8) * DIM, &ldsA[(w * 32 + j * 8) * 64]);
            gload16(gB + (size_t)(j * 8) * DIM, &ldsB[(w * 32 + j * 8) * 64]);
        }
        gA += 64; gB += 64;
        __syncthreads();
#pragma unroll
        for (int kk = 0; kk < 2; kk++) {
            bf16x8 af[4], bfr[4];
#pragma unroll
            for (int m = 0; m < 4; m++) {
                const int row = wr + m * 16 + fr;
                af[m] = *reinterpret_cast<const bf16x8*>(&ldsA[row * 64 + 8 * ((kk * 4 + c0) ^ sx)]);
            }
#pragma unroll
            for (int n = 0; n < 4; n++) {
                const int row = wc + n * 16 + fr;
                bfr[n] = *reinterpret_cast<const bf16x8*>(&ldsB[row * 64 + 8 * ((kk * 4 + c0) ^ sx)]);
            }
#pragma unroll
            for (int m = 0; m < 4; m++)
#pragma unroll
                for (int n = 0; n < 4; n++)
                    acc[m][n] = __builtin_amdgcn_mfma_f32_16x16x32_bf16(af[m], bfr[n], acc[m][n], 0, 0, 0);
        }
        __syncthreads();
    }

    if (!is_tri) {
        // ---- loss epilogue ----
        const float POS_THR = (float)(1.0 - 1e-5);
        float s = 0.f;
#pragma unroll
        for (int m = 0; m < 4; m++)
#pragma unroll
            for (int n = 0; n < 4; n++)
#pragma unroll
                for (int v = 0; v < 4; v++) {
                    const float x = acc[m][n][v];
                    s += (x < POS_THR ? 1.0f - x : 0.0f) + (x > 0.5f ? x : 0.0f);
                }
#pragma unroll
        for (int off = 32; off; off >>= 1) s += __shfl_down(s, off);
        if (l == 0) red[w] = s;
        __syncthreads();
        if (t == 0) loss_partial[bid - tb] = red[0] + red[1] + red[2] + red[3];
    } else {
        // ---- tri argmax epilogue ----
        // C/D mapping: col = lane&15 (+n*16), row = (lane>>4)*4 + v (+m*16)
#pragma unroll
        for (int m = 0; m < 4; m++)
#pragma unroll
            for (int v = 0; v < 4; v++) {
                const int rlocal = m * 16 + ((l >> 4) << 2) + v;    // 0..63 within wave
                const int grow = rowbase + wr + rlocal;
                float best = -3.0f;
                int bcol = 0x7FFFFFFF;
#pragma unroll
                for (int n = 0; n < 4; n++) {
                    const int gcol = colbase + wc + n * 16 + (l & 15);
                    const float x = acc[m][n][v];
                    const bool valid = (gcol != grow);              // exclude diagonal
                    if (valid && (x > best || (x == best && gcol < bcol))) { best = x; bcol = gcol; }
                }
#pragma unroll
                for (int mask = 1; mask < 16; mask <<= 1) {         // 16 lanes hold this row
                    const float ob = __shfl_xor(best, mask);
                    const int   oc = __shfl_xor(bcol, mask);
                    if (ob > best || (ob == best && oc < bcol)) { best = ob; bcol = oc; }
                }
                if ((l & 15) == 0) lds_pack[w][rlocal] = packkey(best, bcol);
            }

        if (by < bx) {   // col-max: argmax over rows of panel by, for cols of panel bx
#pragma unroll
            for (int n = 0; n < 4; n++) {
                float cbest = -3.0f;
                int crow = 0x7FFFFFFF;
#pragma unroll
                for (int m = 0; m < 4; m++)
#pragma unroll
                    for (int v = 0; v < 4; v++) {
                        const int grow = rowbase + wr + m * 16 + ((l >> 4) << 2) + v;
                        const float x = acc[m][n][v];
                        if (x > cbest || (x == cbest && grow < crow)) { cbest = x; crow = grow; }
                    }
#pragma unroll
                for (int mask = 16; mask < 64; mask <<= 1) {        // merge 4 row-groups
                    const float ob = __shfl_xor(cbest, mask);
                    const int   oc = __shfl_xor(crow, mask);
                    if (ob > cbest || (ob == cbest && oc < crow)) { cbest = ob; crow = oc; }
                }
                if ((l >> 4) == 0) colpack[w][n * 16 + l] = packkey(cbest, crow);
            }
        }
        __syncthreads();

        if (t < 128) {
            const int half = t >> 6;                  // waves {0,1}: rows 0-63; {2,3}: 64-127
            const unsigned long long p0 = lds_pack[half * 2][t & 63];
            const unsigned long long p1 = lds_pack[half * 2 + 1][t & 63];
            part[(size_t)bx * NPTS + (unsigned)(rowbase + t)] = (p0 > p1) ? p0 : p1;
            if (by < bx) {
                const int h = t >> 6;                 // waves {0,2}: wc=0; {1,3}: wc=64
                const unsigned long long c0_ = colpack[h][t & 63];
                const unsigned long long c1_ = colpack[h + 2][t & 63];
                part[(size_t)by * NPTS + (unsigned)(colbase + t)] = (c0_ > c1_) ? c0_ : c1_;
            }
        }
    }
}

// ---- per-row: combine 64 tile-maxes -> nn idx -> exact fp32 distance -> -log ----
__global__ __launch_bounds__(256) void nn_reg_kernel(
    const float* __restrict__ q, const unsigned long long* __restrict__ part,
    float* __restrict__ reg_partial)
{
    __shared__ float red[4];
    const int t = threadIdx.x, l = t & 63, w = t >> 6;
    const int row = blockIdx.x * 4 + w;
    unsigned long long p = part[(size_t)l * NPTS + (unsigned)row];
#pragma unroll
    for (int mask = 1; mask < 64; mask <<= 1) {
        const unsigned long long o = __shfl_xor(p, mask);
        if (o > p) p = o;
    }
    const int col = (int)(~(unsigned)(p & 0xFFFFFFFFull));
    const float4* q4 = reinterpret_cast<const float4*>(q);
    const float4 a = q4[row * 64 + l];
    const float4 b = q4[col * 64 + l];
    const float dx = a.x - b.x + 1e-6f;
    const float dy = a.y - b.y + 1e-6f;
    const float dz = a.z - b.z + 1e-6f;
    const float dw = a.w - b.w + 1e-6f;
    float s = dx * dx + dy * dy + dz * dz + dw * dw;
#pragma unroll
    for (int mask = 32; mask; mask >>= 1) s += __shfl_xor(s, mask);
    if (l == 0) red[w] = -0.5f * logf(s);   // -log(sqrt(s))
    __syncthreads();
    if (t == 0) reg_partial[blockIdx.x] = red[0] + red[1] + red[2] + red[3];
}

// ---- final double-precision reduction of partials ---------------------------
__global__ __launch_bounds__(256) void finalize_kernel(
    const float* __restrict__ lp, const float* __restrict__ rp, float* __restrict__ out)
{
    const int t = threadIdx.x, l = t & 63, w = t >> 6;
    double s1 = 0.0, s2 = 0.0;
    for (int i = t; i < 4096; i += 256) s1 += (double)lp[i];
    for (int i = t; i < 2048; i += 256) s2 += (double)rp[i];
#pragma unroll
    for (int mask = 32; mask; mask >>= 1) {
        s1 += __shfl_xor(s1, mask);
        s2 += __shfl_xor(s2, mask);
    }
    __shared__ double r1[4], r2[4];
    if (l == 0) { r1[w] = s1; r2[w] = s2; }
    __syncthreads();
    if (t == 0) {
        out[0] = (float)((r1[0] + r1[1] + r1[2] + r1[3]) / (double)NPTS);
        out[1] = (float)((r2[0] + r2[1] + r2[2] + r2[3]) / (double)NPTS);
    }
}

extern "C" void kernel_launch(void* const* d_in, const int* in_sizes, int n_in,
                              void* d_out, int out_size, void* d_ws, size_t ws_size,
                              hipStream_t stream)
{
    const float* q = (const float*)d_in[0];
    const float* k = (const float*)d_in[1];
    char* ws = (char*)d_ws;
    unsigned short* qbf = (unsigned short*)ws;                          // 4 MB
    unsigned short* kbf = (unsigned short*)(ws + (4u << 20));           // 4 MB
    unsigned long long* part = (unsigned long long*)(ws + (8u << 20));  // [64][8192] u64 = 4 MB
    float* lp = (float*)(ws + (12u << 20));                             // 4096 floats
    float* rp = (float*)(ws + (12u << 20) + (16u << 10));               // 2048 floats
    float* out = (float*)d_out;

    convert_kernel<<<4096, 256, 0, stream>>>(q, k, qbf, kbf);
    sim_merged_kernel<<<NGRID, 256, 0, stream>>>(qbf, kbf, lp, part);
    nn_reg_kernel<<<2048, 256, 0, stream>>>(q, part, rp);
    finalize_kernel<<<1, 256, 0, stream>>>(lp, rp, out);
}

// Round 8
// 113.183 us; speedup vs baseline: 1.5292x; 1.0499x over previous
//
#include <hip/hip_runtime.h>

// Problem: N=8192 points, D=256 dims, fp32 inputs (L2-normalized rows).
// out[0] = sum_{i,j} [ (s<1-1e-5 ? 1-s : 0) + (s>0.5 ? s : 0) ] / N,  s = q_i . k_j
// out[1] = -mean_i log( sqrt( sum_d (q_i[d] - q_nn(i)[d] + 1e-6)^2 ) ),
//          nn(i) = argmax_{j != i} q_i . q_j   (first index on ties)
//
// Round 8: merged dispatch (round 7) + BK=32 DOUBLE-BUFFER at the SAME LDS
// footprint (2x[128x32] per matrix = 32KB; occupancy preserved -- the one
// resource rounds 3-5 proved sacred). Stage(i+1) issues ~250cy before the
// barrier that drains it (under 16 MFMA + 8 ds_read), hiding L2/L3 latency
// that the single-buffer schedule exposed in full at every K-iter.
// Swizzle for 64B rows: physical 16B-slot = logical ^ ((row>>1)&3); inverse
// on per-lane global source, linear gload_lds dest, same XOR on ds_read.

typedef __attribute__((ext_vector_type(8))) short bf16x8;
typedef __attribute__((ext_vector_type(4))) float f32x4;

static constexpr int NPTS = 8192;
static constexpr int DIM  = 256;
static constexpr int NTRI = 2080;            // 64*65/2 triangle tiles
static constexpr int NLOSS = 4096;           // 64*64 loss tiles
static constexpr int NGRID = NTRI + NLOSS;   // 6176

__device__ __forceinline__ unsigned short f2bf(float f) {
    unsigned u = __float_as_uint(f);
    u += 0x7FFFu + ((u >> 16) & 1u);   // RNE; inputs are finite
    return (unsigned short)(u >> 16);
}

// async global->LDS, 16B per lane; LDS dest = wave-uniform base + lane*16
__device__ __forceinline__ void gload16(const unsigned short* g, unsigned short* lds) {
    __builtin_amdgcn_global_load_lds(
        (const __attribute__((address_space(1))) unsigned int*)g,
        (__attribute__((address_space(3))) unsigned int*)lds, 16, 0, 0);
}

__device__ __forceinline__ unsigned long long packkey(float v, int idx) {
    unsigned ub = __float_as_uint(v);
    unsigned key = (ub & 0x80000000u) ? ~ub : (ub | 0x80000000u);  // order-preserving
    return ((unsigned long long)key << 32) | (unsigned)(~idx);     // larger val, then smaller idx
}

// ---- fp32 -> bf16 conversion of q and k -------------------------------------
__global__ __launch_bounds__(256) void convert_kernel(
    const float* __restrict__ q, const float* __restrict__ k,
    unsigned short* __restrict__ qbf, unsigned short* __restrict__ kbf)
{
    const int idx = blockIdx.x * 256 + threadIdx.x;
    const int half = NPTS * DIM / 4;
    const float* src = (idx < half) ? q : k;
    unsigned short* dst = (idx < half) ? qbf : kbf;
    const int i = (idx < half) ? idx : idx - half;
    float4 v = reinterpret_cast<const float4*>(src)[i];
    ushort4 o;
    o.x = f2bf(v.x); o.y = f2bf(v.y); o.z = f2bf(v.z); o.w = f2bf(v.w);
    reinterpret_cast<ushort4*>(dst)[i] = o;
}

// ---- merged GEMM: 128x128 tile, BK=32 dbuf, 4 waves, shared K-loop ----------
__global__ __launch_bounds__(256, 4) void sim_merged_kernel(
    const unsigned short* __restrict__ Qb,  // [N][D] bf16 bits
    const unsigned short* __restrict__ Kb,  // [N][D] bf16 bits
    float* __restrict__ loss_partial,       // [4096]
    unsigned long long* __restrict__ part)  // [64][8192]
{
    __shared__ __align__(16) unsigned short ldsA[2][128 * 32];   // 16 KB
    __shared__ __align__(16) unsigned short ldsB[2][128 * 32];   // 16 KB
    __shared__ unsigned long long lds_pack[4][64];   // row-max per wave (tri)
    __shared__ unsigned long long colpack[4][64];    // col-max per wave (tri)
    __shared__ float red[4];                         // loss reduce

    const int t  = threadIdx.x;
    const int l  = t & 63;
    const int w  = t >> 6;
    const int bid = blockIdx.x;

    // Bresenham 2:1 interleave of 4096 loss + 2080 tri blocks
    const int tb = (int)(((long long)bid * NTRI) / NGRID);
    const int ta = (int)(((long long)(bid + 1) * NTRI) / NGRID);
    const bool is_tri = (ta > tb);

    int by, bx;
    const unsigned short* Bsrc;
    if (is_tri) {
        int r0 = tb;                       // tri index 0..2079: row by has 64-by tiles
        by = 0;
        while (r0 >= 64 - by) { r0 -= 64 - by; ++by; }
        bx = by + r0;
        Bsrc = Qb;
    } else {
        const int li = bid - tb;           // loss index 0..4095
        by = li >> 6; bx = li & 63;
        Bsrc = Kb;
    }

    const int rowbase = by << 7;
    const int colbase = bx << 7;
    const int wr = (w >> 1) << 6;
    const int wc = (w & 1) << 6;

    // staging: wave w covers rows [w*32,+32) in 2 issues of 16 rows per matrix.
    // lane l -> row-in-issue = l>>2, 16B slot = l&3 (rows are 64B = 4 slots).
    // logical 16B slot = (l&3) ^ ((l>>3)&3)  [inverse of read swizzle]
    const int srow = w * 32 + (l >> 2);
    const int scol = 8 * ((l & 3) ^ ((l >> 3) & 3));
    const unsigned short* gA = Qb   + (size_t)(rowbase + srow) * DIM + scol;
    const unsigned short* gB = Bsrc + (size_t)(colbase + srow) * DIM + scol;

    f32x4 acc[4][4];
#pragma unroll
    for (int m = 0; m < 4; m++)
#pragma unroll
        for (int n = 0; n < 4; n++) acc[m][n] = (f32x4){0.f, 0.f, 0.f, 0.f};

    const int fr  = l & 15;            // fragment row within 16
    const int c0  = l >> 4;            // k-slot 0..3 (8 elems each)
    const int sx2 = (fr >> 1) & 3;     // read-side swizzle: slot ^= (row>>1)&3

    auto STAGE = [&](int tt) {         // stage K-iter tt into buf tt&1 (async)
        const int buf = tt & 1;
        const int koff = tt * 32;
#pragma unroll
        for (int j = 0; j < 2; j++) {
            gload16(gA + koff + (size_t)(j * 16) * DIM, &ldsA[buf][(w * 32 + j * 16) * 32]);
            gload16(gB + koff + (size_t)(j * 16) * DIM, &ldsB[buf][(w * 32 + j * 16) * 32]);
        }
    };

    STAGE(0);
    __syncthreads();                   // prologue drain (once per block)

    for (int i = 0; i < 8; i++) {
        if (i < 7) STAGE(i + 1);       // issue-early; drained at end-of-iter barrier
        const unsigned short* bufA = &ldsA[i & 1][0];
        const unsigned short* bufB = &ldsB[i & 1][0];
        bf16x8 af[4], bfr[4];
#pragma unroll
        for (int m = 0; m < 4; m++) {
            const int row = wr + m * 16 + fr;
            af[m] = *reinterpret_cast<const bf16x8*>(&bufA[row * 32 + 8 * (c0 ^ sx2)]);
        }
#pragma unroll
        for (int n = 0; n < 4; n++) {
            const int row = wc + n * 16 + fr;
            bfr[n] = *reinterpret_cast<const bf16x8*>(&bufB[row * 32 + 8 * (c0 ^ sx2)]);
        }
#pragma unroll
        for (int m = 0; m < 4; m++)
#pragma unroll
            for (int n = 0; n < 4; n++)
                acc[m][n] = __builtin_amdgcn_mfma_f32_16x16x32_bf16(af[m], bfr[n], acc[m][n], 0, 0, 0);
        // barrier: (1) all waves done reading buf[i&1] before iter i+1 overwrites
        // buf[(i+1)&1] (prev parity, protected by PREVIOUS barrier) -- distance-2
        // reuse means one barrier/iter suffices; (2) implicit vmcnt drain lands
        // stage(i+1) (issued ~250cy ago, under MFMA+ds_read).
        __syncthreads();
    }

    if (!is_tri) {
        // ---- loss epilogue ----
        const float POS_THR = (float)(1.0 - 1e-5);
        float s = 0.f;
#pragma unroll
        for (int m = 0; m < 4; m++)
#pragma unroll
            for (int n = 0; n < 4; n++)
#pragma unroll
                for (int v = 0; v < 4; v++) {
                    const float x = acc[m][n][v];
                    s += (x < POS_THR ? 1.0f - x : 0.0f) + (x > 0.5f ? x : 0.0f);
                }
#pragma unroll
        for (int off = 32; off; off >>= 1) s += __shfl_down(s, off);
        if (l == 0) red[w] = s;
        __syncthreads();
        if (t == 0) loss_partial[bid - tb] = red[0] + red[1] + red[2] + red[3];
    } else {
        // ---- tri argmax epilogue ----
        // C/D mapping: col = lane&15 (+n*16), row = (lane>>4)*4 + v (+m*16)
#pragma unroll
        for (int m = 0; m < 4; m++)
#pragma unroll
            for (int v = 0; v < 4; v++) {
                const int rlocal = m * 16 + ((l >> 4) << 2) + v;    // 0..63 within wave
                const int grow = rowbase + wr + rlocal;
                float best = -3.0f;
                int bcol = 0x7FFFFFFF;
#pragma unroll
                for (int n = 0; n < 4; n++) {
                    const int gcol = colbase + wc + n * 16 + (l & 15);
                    const float x = acc[m][n][v];
                    const bool valid = (gcol != grow);              // exclude diagonal
                    if (valid && (x > best || (x == best && gcol < bcol))) { best = x; bcol = gcol; }
                }
#pragma unroll
                for (int mask = 1; mask < 16; mask <<= 1) {         // 16 lanes hold this row
                    const float ob = __shfl_xor(best, mask);
                    const int   oc = __shfl_xor(bcol, mask);
                    if (ob > best || (ob == best && oc < bcol)) { best = ob; bcol = oc; }
                }
                if ((l & 15) == 0) lds_pack[w][rlocal] = packkey(best, bcol);
            }

        if (by < bx) {   // col-max: argmax over rows of panel by, for cols of panel bx
#pragma unroll
            for (int n = 0; n < 4; n++) {
                float cbest = -3.0f;
                int crow = 0x7FFFFFFF;
#pragma unroll
                for (int m = 0; m < 4; m++)
#pragma unroll
                    for (int v = 0; v < 4; v++) {
                        const int grow = rowbase + wr + m * 16 + ((l >> 4) << 2) + v;
                        const float x = acc[m][n][v];
                        if (x > cbest || (x == cbest && grow < crow)) { cbest = x; crow = grow; }
                    }
#pragma unroll
                for (int mask = 16; mask < 64; mask <<= 1) {        // merge 4 row-groups
                    const float ob = __shfl_xor(cbest, mask);
                    const int   oc = __shfl_xor(crow, mask);
                    if (ob > cbest || (ob == cbest && oc < crow)) { cbest = ob; crow = oc; }
                }
                if ((l >> 4) == 0) colpack[w][n * 16 + l] = packkey(cbest, crow);
            }
        }
        __syncthreads();

        if (t < 128) {
            const int half = t >> 6;                  // waves {0,1}: rows 0-63; {2,3}: 64-127
            const unsigned long long p0 = lds_pack[half * 2][t & 63];
            const unsigned long long p1 = lds_pack[half * 2 + 1][t & 63];
            part[(size_t)bx * NPTS + (unsigned)(rowbase + t)] = (p0 > p1) ? p0 : p1;
            if (by < bx) {
                const int h = t >> 6;                 // waves {0,2}: wc=0; {1,3}: wc=64
                const unsigned long long c0_ = colpack[h][t & 63];
                const unsigned long long c1_ = colpack[h + 2][t & 63];
                part[(size_t)by * NPTS + (unsigned)(colbase + t)] = (c0_ > c1_) ? c0_ : c1_;
            }
        }
    }
}

// ---- per-row: combine 64 tile-maxes -> nn idx -> exact fp32 distance -> -log ----
__global__ __launch_bounds__(256) void nn_reg_kernel(
    const float* __restrict__ q, const unsigned long long* __restrict__ part,
    float* __restrict__ reg_partial)
{
    __shared__ float red[4];
    const int t = threadIdx.x, l = t & 63, w = t >> 6;
    const int row = blockIdx.x * 4 + w;
    unsigned long long p = part[(size_t)l * NPTS + (unsigned)row];
#pragma unroll
    for (int mask = 1; mask < 64; mask <<= 1) {
        const unsigned long long o = __shfl_xor(p, mask);
        if (o > p) p = o;
    }
    const int col = (int)(~(unsigned)(p & 0xFFFFFFFFull));
    const float4* q4 = reinterpret_cast<const float4*>(q);
    const float4 a = q4[row * 64 + l];
    const float4 b = q4[col * 64 + l];
    const float dx = a.x - b.x + 1e-6f;
    const float dy = a.y - b.y + 1e-6f;
    const float dz = a.z - b.z + 1e-6f;
    const float dw = a.w - b.w + 1e-6f;
    float s = dx * dx + dy * dy + dz * dz + dw * dw;
#pragma unroll
    for (int mask = 32; mask; mask >>= 1) s += __shfl_xor(s, mask);
    if (l == 0) red[w] = -0.5f * logf(s);   // -log(sqrt(s))
    __syncthreads();
    if (t == 0) reg_partial[blockIdx.x] = red[0] + red[1] + red[2] + red[3];
}

// ---- final double-precision reduction of partials ---------------------------
__global__ __launch_bounds__(256) void finalize_kernel(
    const float* __restrict__ lp, const float* __restrict__ rp, float* __restrict__ out)
{
    const int t = threadIdx.x, l = t & 63, w = t >> 6;
    double s1 = 0.0, s2 = 0.0;
    for (int i = t; i < 4096; i += 256) s1 += (double)lp[i];
    for (int i = t; i < 2048; i += 256) s2 += (double)rp[i];
#pragma unroll
    for (int mask = 32; mask; mask >>= 1) {
        s1 += __shfl_xor(s1, mask);
        s2 += __shfl_xor(s2, mask);
    }
    __shared__ double r1[4], r2[4];
    if (l == 0) { r1[w] = s1; r2[w] = s2; }
    __syncthreads();
    if (t == 0) {
        out[0] = (float)((r1[0] + r1[1] + r1[2] + r1[3]) / (double)NPTS);
        out[1] = (float)((r2[0] + r2[1] + r2[2] + r2[3]) / (double)NPTS);
    }
}

extern "C" void kernel_launch(void* const* d_in, const int* in_sizes, int n_in,
                              void* d_out, int out_size, void* d_ws, size_t ws_size,
                              hipStream_t stream)
{
    const float* q = (const float*)d_in[0];
    const float* k = (const float*)d_in[1];
    char* ws = (char*)d_ws;
    unsigned short* qbf = (unsigned short*)ws;                          // 4 MB
    unsigned short* kbf = (unsigned short*)(ws + (4u << 20));           // 4 MB
    unsigned long long* part = (unsigned long long*)(ws + (8u << 20));  // [64][8192] u64 = 4 MB
    float* lp = (float*)(ws + (12u << 20));                             // 4096 floats
    float* rp = (float*)(ws + (12u << 20) + (16u << 10));               // 2048 floats
    float* out = (float*)d_out;

    convert_kernel<<<4096, 256, 0, stream>>>(q, k, qbf, kbf);
    sim_merged_kernel<<<NGRID, 256, 0, stream>>>(qbf, kbf, lp, part);
    nn_reg_kernel<<<2048, 256, 0, stream>>>(q, part, rp);
    finalize_kernel<<<1, 256, 0, stream>>>(lp, rp, out);
}